// Round 19
// baseline (100.120 us; speedup 1.0000x reference)
//
#include <hip/hip_runtime.h>
#include <hip/hip_bf16.h>
#include <cstdint>

#define B_   8
#define C_   128
#define H_   64
#define W_   64
#define NPT  9
#define OC   256
#define K_   (C_*NPT)   // 1152
#define HW   (H_*W_)    // 4096
#define XTPB 557568     // 66*66*128 elements per batch (padded, channel-last)

typedef __attribute__((ext_vector_type(8))) short short8;
typedef __attribute__((ext_vector_type(4))) float f32x4;
typedef __attribute__((ext_vector_type(4))) unsigned int u32x4;

static __device__ __forceinline__ unsigned short f2bf(float f) {
    union { float f; unsigned u; } a; a.f = f;
    unsigned r = a.u + 0x7fffu + ((a.u >> 16) & 1u);   // RNE
    return (unsigned short)(r >> 16);
}
static __device__ __forceinline__ float bf2f(unsigned short u) {
    union { unsigned u; float f; } a; a.u = ((unsigned)u) << 16;
    return a.f;
}

// ---------------- Kernel T2: x f32 -> padded channel-last bf16 hi/lo, + border zeroing (verbatim R18) ----------------
__global__ __launch_bounds__(256) void k_transpose2(const float* __restrict__ x,
                                                    unsigned short* __restrict__ xh,
                                                    unsigned short* __restrict__ xl) {
    __shared__ float sp[128][65];
    int b = blockIdx.x >> 6, i = blockIdx.x & 63;
    int t = threadIdx.x;
    const float* xb = x + (size_t)b * C_ * HW + i * 64;
#pragma unroll
    for (int it = 0; it < 8; ++it) {
        int q = it * 256 + t;
        int c = q >> 4, j4 = q & 15;
        *(f32x4*)&sp[c][j4 * 4] = *(const f32x4*)(xb + (size_t)c * HW + j4 * 4);
    }
    __syncthreads();
    size_t obase = (size_t)b * XTPB + ((size_t)(i + 1) * 66 + 1) * 128;
#pragma unroll
    for (int it = 0; it < 4; ++it) {
        int q = it * 256 + t;
        int j = q >> 4, cg = q & 15;
        u32x4 ph, pl;
#pragma unroll
        for (int p2 = 0; p2 < 4; ++p2) {
            float a = sp[cg * 8 + p2 * 2][j];
            float bb = sp[cg * 8 + p2 * 2 + 1][j];
            unsigned short ah = f2bf(a), bh = f2bf(bb);
            unsigned short al = f2bf(a - bf2f(ah)), bl = f2bf(bb - bf2f(bh));
            ph[p2] = (uint32_t)ah | ((uint32_t)bh << 16);
            pl[p2] = (uint32_t)al | ((uint32_t)bl << 16);
        }
        *(u32x4*)(xh + obase + (size_t)j * 128 + cg * 8) = ph;
        *(u32x4*)(xl + obase + (size_t)j * 128 + cg * 8) = pl;
    }
    size_t rowb = (size_t)b * XTPB + (size_t)(i + 1) * 66 * 128;
    if (t < 128) {
        xh[rowb + t] = 0; xl[rowb + t] = 0;
    } else {
        xh[rowb + 65 * 128 + (t - 128)] = 0; xl[rowb + 65 * 128 + (t - 128)] = 0;
    }
    if (i == 0) {
        size_t r0b = (size_t)b * XTPB;
        for (int e = t; e < 8448; e += 256) { xh[r0b + e] = 0; xl[r0b + e] = 0; }
    }
    if (i == 63) {
        size_t r65 = (size_t)b * XTPB + (size_t)65 * 66 * 128;
        for (int e = t; e < 8448; e += 256) { xh[r65 + e] = 0; xl[r65 + e] = 0; }
    }
}

// ---------------- Kernel PW2: offset-conv weights -> bf16 hi/lo [32][9][128], pre-swizzled (verbatim) ----------------
__global__ __launch_bounds__(256) void k_prepow2(const float* __restrict__ pw,
                                                 unsigned short* __restrict__ wh,
                                                 unsigned short* __restrict__ wl) {
    int idx = blockIdx.x * 256 + threadIdx.x;   // < 36864
    int o = idx / 1152, kp = idx - o * 1152;
    int tp = kp >> 7, c = kp & 127;
    float v = (o < 18) ? pw[o * K_ + c * 9 + tp] : 0.f;
    unsigned short hi = f2bf(v);
    unsigned short lo = f2bf(v - bf2f(hi));
    int db = (o * 2304 + tp * 256 + ((c * 2) ^ ((o & 7) << 4))) >> 1;  // element index
    wh[db] = hi;
    wl[db] = lo;
}

// ---------------- Kernel OG: offset conv as 9-shift MFMA GEMM, 4-chain bf16 split (verbatim R17/R18) ----------------
__global__ __launch_bounds__(256) void k_offgemm2(const unsigned short* __restrict__ xh,
                                                  const unsigned short* __restrict__ xl,
                                                  const unsigned short* __restrict__ wh,
                                                  const unsigned short* __restrict__ wl,
                                                  const float* __restrict__ pb,
                                                  float* __restrict__ off) {
    __shared__ __align__(16) char smem[81920];
    int bid = blockIdx.x;
    int wg = (bid & 7) * 32 + (bid >> 3);
    int b = wg >> 5;
    int i0 = (wg & 31) * 2;
    int tid = threadIdx.x;
    int wv = tid >> 6, lane = tid & 63;
    int lrow = lane & 15, lg = lane >> 4;
    const char* xhb = (const char*)(xh + (size_t)b * XTPB);
    const char* xlb = (const char*)(xl + (size_t)b * XTPB);
    const char* whb = (const char*)wh;
    const char* wlb = (const char*)wl;

    f32x4 zero = {0.f, 0.f, 0.f, 0.f};
    f32x4 acc[2][2];
#pragma unroll
    for (int m = 0; m < 2; ++m)
#pragma unroll
        for (int n = 0; n < 2; ++n) acc[m][n] = zero;

    for (int tpt = 0; tpt < 9; ++tpt) {
        int dh = tpt / 3 - 1, dw = tpt % 3 - 1;
#pragma unroll
        for (int q = 0; q < 8; ++q) {
            int ch = q * 256 + tid;
            int row = ch >> 4, slot = ch & 15;
            int ri = i0 + (row >> 6) + dh + 1;
            int ci = (row & 63) + dw + 1;
            int src = (ri * 66 + ci) * 256 + ((slot * 16) ^ ((row & 7) << 4));
            __builtin_amdgcn_global_load_lds(
                (const __attribute__((address_space(1))) uint32_t*)(xhb + src),
                (__attribute__((address_space(3))) uint32_t*)(smem + ch * 16), 16, 0, 0);
            __builtin_amdgcn_global_load_lds(
                (const __attribute__((address_space(1))) uint32_t*)(xlb + src),
                (__attribute__((address_space(3))) uint32_t*)(smem + 32768 + ch * 16), 16, 0, 0);
        }
#pragma unroll
        for (int q = 0; q < 2; ++q) {
            int ch = q * 256 + tid;
            int row = ch >> 4, slot = ch & 15;
            int src = row * 2304 + tpt * 256 + slot * 16;
            __builtin_amdgcn_global_load_lds(
                (const __attribute__((address_space(1))) uint32_t*)(whb + src),
                (__attribute__((address_space(3))) uint32_t*)(smem + 65536 + ch * 16), 16, 0, 0);
            __builtin_amdgcn_global_load_lds(
                (const __attribute__((address_space(1))) uint32_t*)(wlb + src),
                (__attribute__((address_space(3))) uint32_t*)(smem + 73728 + ch * 16), 16, 0, 0);
        }
        __syncthreads();
#pragma unroll
        for (int ks = 0; ks < 4; ++ks) {
            short8 ah[2], al[2], bh[2], bl[2];
#pragma unroll
            for (int m = 0; m < 2; ++m) {
                int row = wv * 32 + m * 16 + lrow;
                int byt = (ks * 64 + lg * 16) ^ ((row & 7) << 4);
                ah[m] = *(const short8*)(smem + row * 256 + byt);
                al[m] = *(const short8*)(smem + 32768 + row * 256 + byt);
            }
#pragma unroll
            for (int n = 0; n < 2; ++n) {
                int row = n * 16 + lrow;
                int byt = (ks * 64 + lg * 16) ^ ((row & 7) << 4);
                bh[n] = *(const short8*)(smem + 65536 + row * 256 + byt);
                bl[n] = *(const short8*)(smem + 73728 + row * 256 + byt);
            }
#pragma unroll
            for (int m = 0; m < 2; ++m)
#pragma unroll
                for (int n = 0; n < 2; ++n) {
                    acc[m][n] = __builtin_amdgcn_mfma_f32_16x16x32_bf16(ah[m], bh[n], acc[m][n], 0, 0, 0);
                    acc[m][n] = __builtin_amdgcn_mfma_f32_16x16x32_bf16(ah[m], bl[n], acc[m][n], 0, 0, 0);
                    acc[m][n] = __builtin_amdgcn_mfma_f32_16x16x32_bf16(al[m], bh[n], acc[m][n], 0, 0, 0);
                    acc[m][n] = __builtin_amdgcn_mfma_f32_16x16x32_bf16(al[m], bl[n], acc[m][n], 0, 0, 0);
                }
        }
        __syncthreads();
    }
#pragma unroll
    for (int n = 0; n < 2; ++n) {
        int oc = n * 16 + lrow;
        if (oc < 18) {
            float bs = pb[oc];
#pragma unroll
            for (int m = 0; m < 2; ++m) {
#pragma unroll
                for (int r = 0; r < 4; ++r) {
                    int px = wv * 32 + m * 16 + lg * 4 + r;
                    int ii = i0 + (px >> 6), jj = px & 63;
                    off[(((size_t)b * 18 + oc) * H_ + ii) * W_ + jj] = acc[m][n][r] + bs;
                }
            }
        }
    }
}

// ---------------- Kernel W: fold BN scale into bf16 weights, K reordered k = n*128 + c (verbatim) ----------------
__global__ __launch_bounds__(256) void k_prepw(const float* __restrict__ cw,
                                               const float* __restrict__ gam,
                                               const float* __restrict__ bet,
                                               const float* __restrict__ mu,
                                               const float* __restrict__ var,
                                               unsigned short* __restrict__ wbf,
                                               float* __restrict__ bias) {
    int idx = blockIdx.x * 256 + threadIdx.x;   // 0 .. 294911
    int oc = idx / K_;
    int r = idx - oc * K_;
    int n = r >> 7;
    int c = r & 127;
    float sc = gam[oc] * rsqrtf(var[oc] + 1e-5f);
    wbf[idx] = f2bf(cw[oc * K_ + c * NPT + n] * sc);
    if (blockIdx.x == 0 && threadIdx.x < OC) {
        int o = threadIdx.x;
        float s = gam[o] * rsqrtf(var[o] + 1e-5f);
        bias[o] = bet[o] - mu[o] * s;
    }
}

// ---------------- Kernel F: fused gather + MFMA GEMM + BN/SiLU, M=128 per block ----------------
// block = (b, row-pair i0): M=128 px, N=256, K in 36 half-steps of 32. Grid 256.
// B machinery BYTE-IDENTICAL to green R14/R16/R18 (3-deep BK=32 rotation, same stageB, same
// barrier skeleton — the element correlated with all correctness failures is untouched).
// A side doubled: A[2][8 slots][128 px][16B] = 32K; gather thread = (s0=tid>>7, px=tid&127),
// 2 granules (s0, s0+4) per thread; same formulas, same k-order -> bit-identical values.
// LDS: A 32K @0 ; B[3][256][64B]=48K @32768 ; soff[2][1152]f32 @81920. 91136 B -> 1 block/CU.
__global__ __launch_bounds__(512, 2) void k_fused(const unsigned short* __restrict__ xh,
                                                  const float* __restrict__ off,
                                                  const unsigned short* __restrict__ wbf,
                                                  const float* __restrict__ bias,
                                                  float* __restrict__ out) {
    __shared__ __align__(16) char smem[91136];
    int bid = blockIdx.x;
    int wg = (bid & 7) * 32 + (bid >> 3);             // batch-per-XCD swizzle (256 = 8*32)
    int b = wg >> 5;
    int i0 = (wg & 31) * 2;
    int tid = threadIdx.x;
    int wv = tid >> 6, lane = tid & 63;
    int lrow = lane & 15, lg = lane >> 4;
    int gpx = tid & 127;                              // gather pixel (0..127)
    int gs0 = tid >> 7;                               // gather slot base (0..3); slots gs0, gs0+4
    int gii = i0 + (gpx >> 6);                        // gather row
    int gjj = gpx & 63;                               // gather col
    const unsigned short* xTb = xh + (size_t)b * XTPB;
    const char* Bb = (const char*)wbf;
    float* soff = (float*)(smem + 81920);             // [2][1152]

    auto stageB = [&](int buf, int hs) {
        char* base = smem + 32768 + buf * 16384;
#pragma unroll
        for (int q = 0; q < 2; ++q) {
            int ch = q * 512 + tid;                   // 1024 chunks of 16B
            int row = ch >> 2, slot = ch & 3;
            int src = row * 2304 + hs * 64 + ((slot ^ (row & 3)) * 16);   // pre-swizzled source
            __builtin_amdgcn_global_load_lds(
                (const __attribute__((address_space(1))) uint32_t*)(Bb + src),
                (__attribute__((address_space(3))) uint32_t*)(base + ch * 16), 16, 0, 0);
        }
    };

    short8 tpa0, tpa1, tpa2, tpa3, tpb0, tpb1, tpb2, tpb3;
    float w00, w11, w01, w10;
    auto gather_issue = [&](int kt) {
        int n = kt >> 1;
        int c8a = (kt & 1) * 8 + gs0;
        int c8b = c8a + 4;
        float ox = soff[(gpx >> 6) * 1152 + n * 64 + gjj];
        float oy = soff[(gpx >> 6) * 1152 + (n + 9) * 64 + gjj];
        float pxf = (float)(gii + n / 3) + ox;
        float pyf = (float)(gjj + n % 3) + oy;
        float fx = floorf(pxf), fy = floorf(pyf);
        int r0 = max(0, min(63, (int)fx));
        int r1 = max(0, min(63, (int)fx + 1));
        int c0 = max(0, min(63, (int)fy));
        int c1 = max(0, min(63, (int)fy + 1));
        float pxc = fminf(fmaxf(pxf, 0.f), 63.f);
        float pyc = fminf(fmaxf(pyf, 0.f), 63.f);
        float ax = 1.f + ((float)r0 - pxc);
        float bx = 1.f - ((float)r1 - pxc);
        float ay = 1.f + ((float)c0 - pyc);
        float by = 1.f - ((float)c1 - pyc);
        w00 = ax * ay; w11 = bx * by; w01 = ax * by; w10 = bx * ay;
        int rb0 = (r0 + 1) * 66, rb1 = (r1 + 1) * 66;
        const unsigned short* ga = xTb + c8a * 8;
        const unsigned short* gb = xTb + c8b * 8;
        tpa0 = *(const short8*)(ga + (size_t)(rb0 + c0 + 1) * C_);
        tpa1 = *(const short8*)(ga + (size_t)(rb1 + c1 + 1) * C_);
        tpa2 = *(const short8*)(ga + (size_t)(rb0 + c1 + 1) * C_);
        tpa3 = *(const short8*)(ga + (size_t)(rb1 + c0 + 1) * C_);
        tpb0 = *(const short8*)(gb + (size_t)(rb0 + c0 + 1) * C_);
        tpb1 = *(const short8*)(gb + (size_t)(rb1 + c1 + 1) * C_);
        tpb2 = *(const short8*)(gb + (size_t)(rb0 + c1 + 1) * C_);
        tpb3 = *(const short8*)(gb + (size_t)(rb1 + c0 + 1) * C_);
    };
    auto bilin1 = [&](const short8& t0, const short8& t1, const short8& t2, const short8& t3) {
        u32x4 pk;
#pragma unroll
        for (int p2 = 0; p2 < 4; ++p2) {
            unsigned short rr[2];
#pragma unroll
            for (int e = 0; e < 2; ++e) {
                int ei = p2 * 2 + e;
                float v = w00 * bf2f((unsigned short)t0[ei])
                        + w11 * bf2f((unsigned short)t1[ei])
                        + w01 * bf2f((unsigned short)t2[ei])
                        + w10 * bf2f((unsigned short)t3[ei]);
                rr[e] = f2bf(v);
            }
            pk[p2] = (uint32_t)rr[0] | ((uint32_t)rr[1] << 16);
        }
        return pk;
    };
    auto bilinear_write = [&](int kt) {
        u32x4 pa = bilin1(tpa0, tpa1, tpa2, tpa3);
        u32x4 pb2 = bilin1(tpb0, tpb1, tpb2, tpb3);
        char* abuf = smem + (kt & 1) * 16384;
        *(u32x4*)(abuf + gs0 * 2048 + gpx * 16) = pa;
        *(u32x4*)(abuf + (gs0 + 4) * 2048 + gpx * 16) = pb2;
    };

    f32x4 zero = {0.f, 0.f, 0.f, 0.f};
    f32x4 acc[8][2];
#pragma unroll
    for (int m = 0; m < 8; ++m)
#pragma unroll
        for (int n = 0; n < 2; ++n) acc[m][n] = zero;

    auto compute_half = [&](int abuf, int bbuf, int h) {
        const char* sa = smem + abuf * 16384;
        const char* sb = smem + 32768 + bbuf * 16384;
        short8 bfr[2];
#pragma unroll
        for (int n = 0; n < 2; ++n) {
            int row = wv * 32 + n * 16 + lrow;
            bfr[n] = *(const short8*)(sb + row * 64 + ((lg ^ (row & 3)) * 16));   // matching swizzled read
        }
#pragma unroll
        for (int m = 0; m < 8; ++m) {
            short8 afr = *(const short8*)(sa + (h * 4 + lg) * 2048 + (m * 16 + lrow) * 16);
#pragma unroll
            for (int n = 0; n < 2; ++n)
                acc[m][n] = __builtin_amdgcn_mfma_f32_16x16x32_bf16(afr, bfr[n], acc[m][n], 0, 0, 0);
        }
    };

    // prologue: off (2 rows) -> LDS; B halves 0,1; then A(0); B half 2
    for (int e = tid; e < 2304; e += 512) {
        int r = e / 1152, rem = e - r * 1152;
        int plane = rem >> 6, jj = rem & 63;
        soff[e] = off[(((size_t)b * 18 + plane) * H_ + (i0 + r)) * W_ + jj];
    }
    stageB(0, 0);
    stageB(1, 1);
    __syncthreads();
    gather_issue(0);
    bilinear_write(0);
    stageB(2, 2);
    __syncthreads();

#pragma unroll 6
    for (int kt = 0; kt < 18; ++kt) {
        const int hs0 = 2 * kt;
        // h0
        if (hs0 + 2 < 36) stageB((hs0 + 2) % 3, hs0 + 2);
        if (kt < 17) gather_issue(kt + 1);
        compute_half(kt & 1, hs0 % 3, 0);
        __syncthreads();
        // h1
        if (hs0 + 3 < 36) stageB((hs0 + 3) % 3, hs0 + 3);
        if (kt < 17) bilinear_write(kt + 1);
        compute_half(kt & 1, (hs0 + 1) % 3, 1);
        __syncthreads();
    }

    // epilogue: bias + SiLU (128 px per wave-column)
#pragma unroll
    for (int n = 0; n < 2; ++n) {
        int oc = wv * 32 + n * 16 + lrow;
        float bs = bias[oc];
#pragma unroll
        for (int m = 0; m < 8; ++m) {
#pragma unroll
            for (int r = 0; r < 4; ++r) {
                int px = m * 16 + lg * 4 + r;
                float v = acc[m][n][r] + bs;
                float sv = v / (1.f + __expf(-v));
                out[((size_t)b * OC + oc) * HW + (i0 + (px >> 6)) * W_ + (px & 63)] = sv;
            }
        }
    }
}

extern "C" void kernel_launch(void* const* d_in, const int* in_sizes, int n_in,
                              void* d_out, int out_size, void* d_ws, size_t ws_size,
                              hipStream_t stream) {
    const float* x   = (const float*)d_in[0];
    const float* pw  = (const float*)d_in[1];
    const float* pb  = (const float*)d_in[2];
    const float* cw  = (const float*)d_in[3];
    const float* gam = (const float*)d_in[4];
    const float* bet = (const float*)d_in[5];
    const float* mu  = (const float*)d_in[6];
    const float* var = (const float*)d_in[7];
    float* out = (float*)d_out;

    char* ws = (char*)d_ws;
    float* off           = (float*)ws;                           // 2,359,296 B
    unsigned short* wbf  = (unsigned short*)(ws + 2359296);      //   589,824 B
    float* bias          = (float*)(ws + 2949120);               //     1,024 B
    unsigned short* whi  = (unsigned short*)(ws + 2950144);      //    73,728 B
    unsigned short* wlo  = (unsigned short*)(ws + 3023872);      //    73,728 B
    unsigned short* xh   = (unsigned short*)(ws + 3097600);      // 8,921,088 B
    unsigned short* xl   = (unsigned short*)(ws + 12018688);     // 8,921,088 B

    hipLaunchKernelGGL(k_transpose2, dim3(512),  dim3(256), 0, stream, x, xh, xl);
    hipLaunchKernelGGL(k_prepow2,    dim3(144),  dim3(256), 0, stream, pw, whi, wlo);
    hipLaunchKernelGGL(k_prepw,      dim3(1152), dim3(256), 0, stream, cw, gam, bet, mu, var, wbf, bias);
    hipLaunchKernelGGL(k_offgemm2,   dim3(256),  dim3(256), 0, stream, xh, xl, whi, wlo, pb, off);
    hipLaunchKernelGGL(k_fused,      dim3(256),  dim3(512), 0, stream, xh, off, wbf, bias, out);
}

// Round 20
// 97.410 us; speedup vs baseline: 1.0278x; 1.0278x over previous
//
#include <hip/hip_runtime.h>
#include <hip/hip_bf16.h>
#include <cstdint>

#define B_   8
#define C_   128
#define H_   64
#define W_   64
#define NPT  9
#define OC   256
#define K_   (C_*NPT)   // 1152
#define HW   (H_*W_)    // 4096
#define XTPB 557568     // 66*66*128 elements per batch (padded, channel-last)

typedef __attribute__((ext_vector_type(8))) short short8;
typedef __attribute__((ext_vector_type(4))) float f32x4;
typedef __attribute__((ext_vector_type(4))) unsigned int u32x4;

static __device__ __forceinline__ unsigned short f2bf(float f) {
    union { float f; unsigned u; } a; a.f = f;
    unsigned r = a.u + 0x7fffu + ((a.u >> 16) & 1u);   // RNE
    return (unsigned short)(r >> 16);
}
static __device__ __forceinline__ float bf2f(unsigned short u) {
    union { unsigned u; float f; } a; a.u = ((unsigned)u) << 16;
    return a.f;
}

// ---------------- Kernel T2: x f32 -> padded channel-last bf16 hi/lo, + border zeroing ----------------
__global__ __launch_bounds__(256) void k_transpose2(const float* __restrict__ x,
                                                    unsigned short* __restrict__ xh,
                                                    unsigned short* __restrict__ xl) {
    __shared__ float sp[128][65];
    int b = blockIdx.x >> 6, i = blockIdx.x & 63;
    int t = threadIdx.x;
    const float* xb = x + (size_t)b * C_ * HW + i * 64;
#pragma unroll
    for (int it = 0; it < 8; ++it) {
        int q = it * 256 + t;
        int c = q >> 4, j4 = q & 15;
        *(f32x4*)&sp[c][j4 * 4] = *(const f32x4*)(xb + (size_t)c * HW + j4 * 4);
    }
    __syncthreads();
    size_t obase = (size_t)b * XTPB + ((size_t)(i + 1) * 66 + 1) * 128;
#pragma unroll
    for (int it = 0; it < 4; ++it) {
        int q = it * 256 + t;
        int j = q >> 4, cg = q & 15;
        u32x4 ph, pl;
#pragma unroll
        for (int p2 = 0; p2 < 4; ++p2) {
            float a = sp[cg * 8 + p2 * 2][j];
            float bb = sp[cg * 8 + p2 * 2 + 1][j];
            unsigned short ah = f2bf(a), bh = f2bf(bb);
            unsigned short al = f2bf(a - bf2f(ah)), bl = f2bf(bb - bf2f(bh));
            ph[p2] = (uint32_t)ah | ((uint32_t)bh << 16);
            pl[p2] = (uint32_t)al | ((uint32_t)bl << 16);
        }
        *(u32x4*)(xh + obase + (size_t)j * 128 + cg * 8) = ph;
        *(u32x4*)(xl + obase + (size_t)j * 128 + cg * 8) = pl;
    }
    size_t rowb = (size_t)b * XTPB + (size_t)(i + 1) * 66 * 128;
    if (t < 128) {
        xh[rowb + t] = 0; xl[rowb + t] = 0;
    } else {
        xh[rowb + 65 * 128 + (t - 128)] = 0; xl[rowb + 65 * 128 + (t - 128)] = 0;
    }
    if (i == 0) {
        size_t r0b = (size_t)b * XTPB;
        for (int e = t; e < 8448; e += 256) { xh[r0b + e] = 0; xl[r0b + e] = 0; }
    }
    if (i == 63) {
        size_t r65 = (size_t)b * XTPB + (size_t)65 * 66 * 128;
        for (int e = t; e < 8448; e += 256) { xh[r65 + e] = 0; xl[r65 + e] = 0; }
    }
}

// ---------------- Kernel PW2: offset-conv weights -> bf16 hi/lo [32][9][128], pre-swizzled ----------------
__global__ __launch_bounds__(256) void k_prepow2(const float* __restrict__ pw,
                                                 unsigned short* __restrict__ wh,
                                                 unsigned short* __restrict__ wl) {
    int idx = blockIdx.x * 256 + threadIdx.x;   // < 36864
    int o = idx / 1152, kp = idx - o * 1152;
    int tp = kp >> 7, c = kp & 127;
    float v = (o < 18) ? pw[o * K_ + c * 9 + tp] : 0.f;
    unsigned short hi = f2bf(v);
    unsigned short lo = f2bf(v - bf2f(hi));
    int db = (o * 2304 + tp * 256 + ((c * 2) ^ ((o & 7) << 4))) >> 1;  // element index
    wh[db] = hi;
    wl[db] = lo;
}

// ---------------- Kernel OG: offset conv as 9-shift MFMA GEMM, 4-chain bf16 split ----------------
__global__ __launch_bounds__(256) void k_offgemm2(const unsigned short* __restrict__ xh,
                                                  const unsigned short* __restrict__ xl,
                                                  const unsigned short* __restrict__ wh,
                                                  const unsigned short* __restrict__ wl,
                                                  const float* __restrict__ pb,
                                                  float* __restrict__ off) {
    __shared__ __align__(16) char smem[81920];
    int bid = blockIdx.x;
    int wg = (bid & 7) * 32 + (bid >> 3);
    int b = wg >> 5;
    int i0 = (wg & 31) * 2;
    int tid = threadIdx.x;
    int wv = tid >> 6, lane = tid & 63;
    int lrow = lane & 15, lg = lane >> 4;
    const char* xhb = (const char*)(xh + (size_t)b * XTPB);
    const char* xlb = (const char*)(xl + (size_t)b * XTPB);
    const char* whb = (const char*)wh;
    const char* wlb = (const char*)wl;

    f32x4 zero = {0.f, 0.f, 0.f, 0.f};
    f32x4 acc[2][2];
#pragma unroll
    for (int m = 0; m < 2; ++m)
#pragma unroll
        for (int n = 0; n < 2; ++n) acc[m][n] = zero;

    for (int tpt = 0; tpt < 9; ++tpt) {
        int dh = tpt / 3 - 1, dw = tpt % 3 - 1;
#pragma unroll
        for (int q = 0; q < 8; ++q) {
            int ch = q * 256 + tid;
            int row = ch >> 4, slot = ch & 15;
            int ri = i0 + (row >> 6) + dh + 1;
            int ci = (row & 63) + dw + 1;
            int src = (ri * 66 + ci) * 256 + ((slot * 16) ^ ((row & 7) << 4));
            __builtin_amdgcn_global_load_lds(
                (const __attribute__((address_space(1))) uint32_t*)(xhb + src),
                (__attribute__((address_space(3))) uint32_t*)(smem + ch * 16), 16, 0, 0);
            __builtin_amdgcn_global_load_lds(
                (const __attribute__((address_space(1))) uint32_t*)(xlb + src),
                (__attribute__((address_space(3))) uint32_t*)(smem + 32768 + ch * 16), 16, 0, 0);
        }
#pragma unroll
        for (int q = 0; q < 2; ++q) {
            int ch = q * 256 + tid;
            int row = ch >> 4, slot = ch & 15;
            int src = row * 2304 + tpt * 256 + slot * 16;
            __builtin_amdgcn_global_load_lds(
                (const __attribute__((address_space(1))) uint32_t*)(whb + src),
                (__attribute__((address_space(3))) uint32_t*)(smem + 65536 + ch * 16), 16, 0, 0);
            __builtin_amdgcn_global_load_lds(
                (const __attribute__((address_space(1))) uint32_t*)(wlb + src),
                (__attribute__((address_space(3))) uint32_t*)(smem + 73728 + ch * 16), 16, 0, 0);
        }
        __syncthreads();
#pragma unroll
        for (int ks = 0; ks < 4; ++ks) {
            short8 ah[2], al[2], bh[2], bl[2];
#pragma unroll
            for (int m = 0; m < 2; ++m) {
                int row = wv * 32 + m * 16 + lrow;
                int byt = (ks * 64 + lg * 16) ^ ((row & 7) << 4);
                ah[m] = *(const short8*)(smem + row * 256 + byt);
                al[m] = *(const short8*)(smem + 32768 + row * 256 + byt);
            }
#pragma unroll
            for (int n = 0; n < 2; ++n) {
                int row = n * 16 + lrow;
                int byt = (ks * 64 + lg * 16) ^ ((row & 7) << 4);
                bh[n] = *(const short8*)(smem + 65536 + row * 256 + byt);
                bl[n] = *(const short8*)(smem + 73728 + row * 256 + byt);
            }
#pragma unroll
            for (int m = 0; m < 2; ++m)
#pragma unroll
                for (int n = 0; n < 2; ++n) {
                    acc[m][n] = __builtin_amdgcn_mfma_f32_16x16x32_bf16(ah[m], bh[n], acc[m][n], 0, 0, 0);
                    acc[m][n] = __builtin_amdgcn_mfma_f32_16x16x32_bf16(ah[m], bl[n], acc[m][n], 0, 0, 0);
                    acc[m][n] = __builtin_amdgcn_mfma_f32_16x16x32_bf16(al[m], bh[n], acc[m][n], 0, 0, 0);
                    acc[m][n] = __builtin_amdgcn_mfma_f32_16x16x32_bf16(al[m], bl[n], acc[m][n], 0, 0, 0);
                }
        }
        __syncthreads();
    }
#pragma unroll
    for (int n = 0; n < 2; ++n) {
        int oc = n * 16 + lrow;
        if (oc < 18) {
            float bs = pb[oc];
#pragma unroll
            for (int m = 0; m < 2; ++m) {
#pragma unroll
                for (int r = 0; r < 4; ++r) {
                    int px = wv * 32 + m * 16 + lg * 4 + r;
                    int ii = i0 + (px >> 6), jj = px & 63;
                    off[(((size_t)b * 18 + oc) * H_ + ii) * W_ + jj] = acc[m][n][r] + bs;
                }
            }
        }
    }
}

// ---------------- Kernel W: fold BN scale into bf16 weights, K reordered k = n*128 + c ----------------
__global__ __launch_bounds__(256) void k_prepw(const float* __restrict__ cw,
                                               const float* __restrict__ gam,
                                               const float* __restrict__ bet,
                                               const float* __restrict__ mu,
                                               const float* __restrict__ var,
                                               unsigned short* __restrict__ wbf,
                                               float* __restrict__ bias) {
    int idx = blockIdx.x * 256 + threadIdx.x;   // 0 .. 294911
    int oc = idx / K_;
    int r = idx - oc * K_;
    int n = r >> 7;
    int c = r & 127;
    float sc = gam[oc] * rsqrtf(var[oc] + 1e-5f);
    wbf[idx] = f2bf(cw[oc * K_ + c * NPT + n] * sc);
    if (blockIdx.x == 0 && threadIdx.x < OC) {
        int o = threadIdx.x;
        float s = gam[o] * rsqrtf(var[o] + 1e-5f);
        bias[o] = bet[o] - mu[o] * s;
    }
}

// ---------------- Kernel F: fused gather + MFMA GEMM + BN/SiLU (R18 verbatim — best green) ----------------
// block = (b, row i): M=64 px, N=256, K in 36 half-steps of 32.
// LDS: A[2][8][64][16B]=16K @0 ; B[3][256][64B]=48K @16384 ; off[1152]f32 @65536. 70144 B.
// Schedule FROZEN (3-deep B rotation + 2 barriers/half-step).
__global__ __launch_bounds__(512, 4) void k_fused(const unsigned short* __restrict__ xh,
                                                  const float* __restrict__ off,
                                                  const unsigned short* __restrict__ wbf,
                                                  const float* __restrict__ bias,
                                                  float* __restrict__ out) {
    __shared__ __align__(16) char smem[70144];
    int bid = blockIdx.x;
    int wg = (bid & 7) * 64 + (bid >> 3);             // batch-per-XCD swizzle
    int b = wg >> 6;
    int i = wg & 63;
    int tid = threadIdx.x;
    int wv = tid >> 6, lane = tid & 63, j = lane;
    int lrow = lane & 15, lg = lane >> 4;
    const unsigned short* xTb = xh + (size_t)b * XTPB;
    const char* Bb = (const char*)wbf;
    float* soff = (float*)(smem + 65536);

    auto stageB = [&](int buf, int hs) {
        char* base = smem + 16384 + buf * 16384;
#pragma unroll
        for (int q = 0; q < 2; ++q) {
            int ch = q * 512 + tid;                   // 1024 chunks of 16B
            int row = ch >> 2, slot = ch & 3;
            int src = row * 2304 + hs * 64 + ((slot ^ (row & 3)) * 16);   // pre-swizzled source
            __builtin_amdgcn_global_load_lds(
                (const __attribute__((address_space(1))) uint32_t*)(Bb + src),
                (__attribute__((address_space(3))) uint32_t*)(base + ch * 16), 16, 0, 0);
        }
    };

    short8 tp0, tp1, tp2, tp3;
    float w00, w11, w01, w10;
    auto gather_issue = [&](int kt) {
        int n = kt >> 1;
        int c8 = (kt & 1) * 8 + wv;
        float ox = soff[n * 64 + j];
        float oy = soff[(n + 9) * 64 + j];
        float pxf = (float)(i + n / 3) + ox;
        float pyf = (float)(j + n % 3) + oy;
        float fx = floorf(pxf), fy = floorf(pyf);
        int r0 = max(0, min(63, (int)fx));
        int r1 = max(0, min(63, (int)fx + 1));
        int c0 = max(0, min(63, (int)fy));
        int c1 = max(0, min(63, (int)fy + 1));
        float pxc = fminf(fmaxf(pxf, 0.f), 63.f);
        float pyc = fminf(fmaxf(pyf, 0.f), 63.f);
        float ax = 1.f + ((float)r0 - pxc);
        float bx = 1.f - ((float)r1 - pxc);
        float ay = 1.f + ((float)c0 - pyc);
        float by = 1.f - ((float)c1 - pyc);
        w00 = ax * ay; w11 = bx * by; w01 = ax * by; w10 = bx * ay;
        const unsigned short* g = xTb + c8 * 8;
        int rb0 = (r0 + 1) * 66, rb1 = (r1 + 1) * 66;
        tp0 = *(const short8*)(g + (size_t)(rb0 + c0 + 1) * C_);
        tp1 = *(const short8*)(g + (size_t)(rb1 + c1 + 1) * C_);
        tp2 = *(const short8*)(g + (size_t)(rb0 + c1 + 1) * C_);
        tp3 = *(const short8*)(g + (size_t)(rb1 + c0 + 1) * C_);
    };
    auto bilinear_write = [&](int kt) {
        u32x4 pk;
#pragma unroll
        for (int p2 = 0; p2 < 4; ++p2) {
            unsigned short rr[2];
#pragma unroll
            for (int e = 0; e < 2; ++e) {
                int ei = p2 * 2 + e;
                float v = w00 * bf2f((unsigned short)tp0[ei])
                        + w11 * bf2f((unsigned short)tp1[ei])
                        + w01 * bf2f((unsigned short)tp2[ei])
                        + w10 * bf2f((unsigned short)tp3[ei]);
                rr[e] = f2bf(v);
            }
            pk[p2] = (uint32_t)rr[0] | ((uint32_t)rr[1] << 16);
        }
        *(u32x4*)(smem + (kt & 1) * 8192 + wv * 1024 + j * 16) = pk;
    };

    f32x4 zero = {0.f, 0.f, 0.f, 0.f};
    f32x4 acc[4][2];
#pragma unroll
    for (int m = 0; m < 4; ++m)
#pragma unroll
        for (int n = 0; n < 2; ++n) acc[m][n] = zero;

    auto compute_half = [&](int abuf, int bbuf, int h) {
        const char* sa = smem + abuf * 8192;
        const char* sb = smem + 16384 + bbuf * 16384;
        short8 afr[4], bfr[2];
#pragma unroll
        for (int m = 0; m < 4; ++m)
            afr[m] = *(const short8*)(sa + (h * 4 + lg) * 1024 + (m * 16 + lrow) * 16);
#pragma unroll
        for (int n = 0; n < 2; ++n) {
            int row = wv * 32 + n * 16 + lrow;
            bfr[n] = *(const short8*)(sb + row * 64 + ((lg ^ (row & 3)) * 16));   // matching swizzled read
        }
#pragma unroll
        for (int m = 0; m < 4; ++m)
#pragma unroll
            for (int n = 0; n < 2; ++n)
                acc[m][n] = __builtin_amdgcn_mfma_f32_16x16x32_bf16(afr[m], bfr[n], acc[m][n], 0, 0, 0);
    };

    // prologue: off -> LDS; B halves 0,1; then A(0); B half 2
    for (int e = tid; e < 1152; e += 512) {
        int plane = e >> 6, jj = e & 63;
        soff[e] = off[(((size_t)b * 18 + plane) * H_ + i) * W_ + jj];
    }
    stageB(0, 0);
    stageB(1, 1);
    __syncthreads();
    gather_issue(0);
    bilinear_write(0);
    stageB(2, 2);
    __syncthreads();

#pragma unroll 6
    for (int kt = 0; kt < 18; ++kt) {
        const int hs0 = 2 * kt;
        // h0
        if (hs0 + 2 < 36) stageB((hs0 + 2) % 3, hs0 + 2);
        if (kt < 17) gather_issue(kt + 1);
        compute_half(kt & 1, hs0 % 3, 0);
        __syncthreads();
        // h1
        if (hs0 + 3 < 36) stageB((hs0 + 3) % 3, hs0 + 3);
        if (kt < 17) bilinear_write(kt + 1);
        compute_half(kt & 1, (hs0 + 1) % 3, 1);
        __syncthreads();
    }

    // epilogue: bias + SiLU
#pragma unroll
    for (int n = 0; n < 2; ++n) {
        int oc = wv * 32 + n * 16 + lrow;
        float bs = bias[oc];
#pragma unroll
        for (int m = 0; m < 4; ++m) {
#pragma unroll
            for (int r = 0; r < 4; ++r) {
                int px = m * 16 + lg * 4 + r;
                float v = acc[m][n][r] + bs;
                float sv = v / (1.f + __expf(-v));
                out[((size_t)b * OC + oc) * HW + i * 64 + px] = sv;
            }
        }
    }
}

extern "C" void kernel_launch(void* const* d_in, const int* in_sizes, int n_in,
                              void* d_out, int out_size, void* d_ws, size_t ws_size,
                              hipStream_t stream) {
    const float* x   = (const float*)d_in[0];
    const float* pw  = (const float*)d_in[1];
    const float* pb  = (const float*)d_in[2];
    const float* cw  = (const float*)d_in[3];
    const float* gam = (const float*)d_in[4];
    const float* bet = (const float*)d_in[5];
    const float* mu  = (const float*)d_in[6];
    const float* var = (const float*)d_in[7];
    float* out = (float*)d_out;

    char* ws = (char*)d_ws;
    float* off           = (float*)ws;                           // 2,359,296 B
    unsigned short* wbf  = (unsigned short*)(ws + 2359296);      //   589,824 B
    float* bias          = (float*)(ws + 2949120);               //     1,024 B
    unsigned short* whi  = (unsigned short*)(ws + 2950144);      //    73,728 B
    unsigned short* wlo  = (unsigned short*)(ws + 3023872);      //    73,728 B
    unsigned short* xh   = (unsigned short*)(ws + 3097600);      // 8,921,088 B
    unsigned short* xl   = (unsigned short*)(ws + 12018688);     // 8,921,088 B

    hipLaunchKernelGGL(k_transpose2, dim3(512),  dim3(256), 0, stream, x, xh, xl);
    hipLaunchKernelGGL(k_prepow2,    dim3(144),  dim3(256), 0, stream, pw, whi, wlo);
    hipLaunchKernelGGL(k_prepw,      dim3(1152), dim3(256), 0, stream, cw, gam, bet, mu, var, wbf, bias);
    hipLaunchKernelGGL(k_offgemm2,   dim3(256),  dim3(256), 0, stream, xh, xl, whi, wlo, pb, off);
    hipLaunchKernelGGL(k_fused,      dim3(512),  dim3(512), 0, stream, xh, off, wbf, bias, out);
}